// Round 10
// baseline (250.794 us; speedup 1.0000x reference)
//
#include <hip/hip_runtime.h>
#include <math.h>

// GAT 2-layer, single head, N=100000, E=1600000, F: 128->64->40.
//   - prep: W1->w1t f16 (transposed); W2->w2t f16 with u2/v2 in cols 40/41;
//     u1/v1 = W1@att fp32
//   - fused dispatch: BIN FIRST (blocks [0,bb)) + gemm1 (fp16 MFMA, A from
//     LDS, B from global w1t (L1-hot), as/ad via x.u1 LDS dot)
//   - fine per-bin counting sort (inline binbase loop) -> exact CSR
//   - fused agg<64> + gemm2: 64 dsts/block, 4 rounds/group, relu'd f16 rows
//     in LDS feed the gemm2 MFMA; as2/ad2 free from cols 40/41
//   - agg<40>: one 16-lane group per dst; fp16 gather

#define NEG_SLOPE 0.2f
#define BIN_SHIFT 10
#define BIN_NODES 1024
#define MAXBINS   128
#define CAPB      17408
#define K1_CHUNK  4096
#define MAXDEG    128
#define AGG_STRIDE 132
#define XS1 136   // gemm1 LDS row stride (f16)
#define XS2 72    // gemm2 LDS row stride (f16)

typedef _Float16 h4_t __attribute__((ext_vector_type(4)));
typedef _Float16 h8_t __attribute__((ext_vector_type(8)));
typedef float    f16x_t __attribute__((ext_vector_type(16)));

__device__ __forceinline__ float lrelu(float v) {
    return v > 0.f ? v : NEG_SLOPE * v;
}

// ---------------- prep (2 blocks) ----------------
__global__ __launch_bounds__(256) void prep_kernel(
    const float* __restrict__ W1, const float* __restrict__ W2,
    const float* __restrict__ as1, const float* __restrict__ ad1,
    const float* __restrict__ as2, const float* __restrict__ ad2,
    _Float16* __restrict__ w1t, _Float16* __restrict__ w2t,
    float* __restrict__ u1, float* __restrict__ v1)
{
    const int tid = threadIdx.x;
    if (blockIdx.x == 0) {
        for (int i = tid; i < 8192; i += 256) {         // w1t[n][k] = W1[k][n]
            int n = i >> 7, k = i & 127;
            w1t[i] = (_Float16)W1[k * 64 + n];
        }
        if (tid < 128) {                                 // u1/v1 = W1 @ att
            float su = 0.f, sv = 0.f;
            for (int n = 0; n < 64; ++n) {
                float w = W1[tid * 64 + n];
                su += w * as1[n];
                sv += w * ad1[n];
            }
            u1[tid] = su; v1[tid] = sv;
        }
    } else {
        __shared__ float u2l[64], v2l[64];
        if (tid < 64) {                                  // u2/v2 = W2 @ att
            float su = 0.f, sv = 0.f;
            for (int n = 0; n < 40; ++n) {
                float w = W2[tid * 40 + n];
                su += w * as2[n];
                sv += w * ad2[n];
            }
            u2l[tid] = su; v2l[tid] = sv;
        }
        __syncthreads();
        for (int i = tid; i < 4096; i += 256) {          // w2t[n][k]
            int n = i >> 6, k = i & 63;
            _Float16 o = (_Float16)0.f;
            if (n < 40)       o = (_Float16)W2[k * 40 + n];
            else if (n == 40) o = (_Float16)u2l[k];
            else if (n == 41) o = (_Float16)v2l[k];
            w2t[i] = o;
        }
    }
}

// ---------------- fused: bin (blocks < bb) + gemm1 (blocks >= bb) ------------
__global__ __launch_bounds__(256) void gemm1_bin_kernel(
    const float* __restrict__ x, const _Float16* __restrict__ w1t,
    const float* __restrict__ u1, const float* __restrict__ v1,
    _Float16* __restrict__ h, float* __restrict__ as_, float* __restrict__ ad_,
    int N, int bb,
    const int* __restrict__ src, const int* __restrict__ dst, int E, int nbins,
    int* __restrict__ bin_cursor, int* __restrict__ binned)
{
    __shared__ __align__(16) char smem[18432];
    const int tid = threadIdx.x;

    if (blockIdx.x >= bb) {
        // ================= GEMM1: h = x @ W1, fp16 MFMA =================
        _Float16* Xs = (_Float16*)smem;              // 64*136 f16 = 17408 B
        float*    Us = (float*)(smem + 17408);       // 512 B
        float*    Vs = (float*)(smem + 17920);       // 512 B
        const int lane = tid & 63;
        const int w = tid >> 6;
        const int rh = w >> 1, ch = w & 1;
        const int m = lane & 31, khalf = lane >> 5;
        const long rowbase = (long)(blockIdx.x - bb) * 64;

        // B prefetch from global (w1t 16KB, L1-hot)
        h8_t bfrag[8];
        {
            const _Float16* bp = w1t + (ch * 32 + m) * 128 + khalf * 8;
#pragma unroll
            for (int kc = 0; kc < 8; ++kc)
                bfrag[kc] = *(const h8_t*)(bp + kc * 16);
        }
        {   // stage Xs: 64 rows x 128 f32 -> f16
            const float4* X4 = (const float4*)x;
            const long gmax = (long)N * 32;
#pragma unroll
            for (int i = 0; i < 8; ++i) {
                int f = tid + i * 256;
                int row = f >> 5, c4 = f & 31;
                long gi = (rowbase + row) * 32 + c4;
                float4 v = (gi < gmax) ? X4[gi] : make_float4(0.f, 0.f, 0.f, 0.f);
                h4_t hv;
                hv.x = (_Float16)v.x; hv.y = (_Float16)v.y;
                hv.z = (_Float16)v.z; hv.w = (_Float16)v.w;
                *(h4_t*)&Xs[row * XS1 + c4 * 4] = hv;
            }
        }
        if (tid < 128) Us[tid] = u1[tid];
        else { int t = tid - 128; Vs[t] = v1[t]; }
        __syncthreads();

        // as/ad: row dot with u1/v1 from staged tile (4 lanes per row)
        {
            const int arow = tid >> 2, apart = tid & 3;
            const _Float16* xr = &Xs[arow * XS1 + apart * 32];
            float ps = 0.f, pd = 0.f;
#pragma unroll
            for (int k = 0; k < 32; k += 4) {
                h4_t xv = *(const h4_t*)(xr + k);
                float4 uu = *(const float4*)&Us[apart * 32 + k];
                float4 vv = *(const float4*)&Vs[apart * 32 + k];
                float x0 = (float)xv.x, x1 = (float)xv.y, x2 = (float)xv.z, x3 = (float)xv.w;
                ps += x0 * uu.x + x1 * uu.y + x2 * uu.z + x3 * uu.w;
                pd += x0 * vv.x + x1 * vv.y + x2 * vv.z + x3 * vv.w;
            }
            ps += __shfl_xor(ps, 1); ps += __shfl_xor(ps, 2);
            pd += __shfl_xor(pd, 1); pd += __shfl_xor(pd, 2);
            if (apart == 0 && rowbase + arow < N) {
                as_[rowbase + arow] = ps;
                ad_[rowbase + arow] = pd;
            }
        }

        const _Float16* ax = &Xs[(rh * 32 + m) * XS1 + khalf * 8];
        f16x_t acc = {};
#pragma unroll
        for (int kc = 0; kc < 8; ++kc) {
            h8_t a = *(const h8_t*)(ax + kc * 16);
            acc = __builtin_amdgcn_mfma_f32_32x32x16_f16(a, bfrag[kc], acc, 0, 0, 0);
        }

        const int col = ch * 32 + m;
#pragma unroll
        for (int r = 0; r < 16; ++r) {
            int rowl = (r & 3) + 8 * (r >> 2) + 4 * khalf;
            long grow = rowbase + rh * 32 + rowl;
            if (grow < N) h[grow * 64 + col] = (_Float16)acc[r];
        }
    } else {
        // ================= BIN: coarse binning, register-cached =========
        int* hist = (int*)smem;
        int* base = (int*)(smem + 512);
        int* lcur = (int*)(smem + 1024);
        const int e0 = blockIdx.x * K1_CHUNK;

        int sreg[16], dreg[16];
#pragma unroll
        for (int k = 0; k < 16; ++k) {
            int e = e0 + tid + k * 256;
            bool ok = e < E;
            dreg[k] = ok ? dst[e] : -1;
            sreg[k] = ok ? src[e] : 0;
        }

        if (tid < nbins) hist[tid] = 0;
        __syncthreads();
#pragma unroll
        for (int k = 0; k < 16; ++k)
            if (dreg[k] >= 0) atomicAdd(&hist[dreg[k] >> BIN_SHIFT], 1);
        __syncthreads();
        if (tid < nbins) {
            int c = hist[tid];
            base[tid] = (c > 0) ? atomicAdd(&bin_cursor[tid], c) : 0;
            lcur[tid] = 0;
        }
        __syncthreads();
#pragma unroll
        for (int k = 0; k < 16; ++k) {
            if (dreg[k] >= 0) {
                int b = dreg[k] >> BIN_SHIFT;
                int o = atomicAdd(&lcur[b], 1);
                int pos = base[b] + o;
                if (pos < CAPB)
                    binned[b * CAPB + pos] =
                        (sreg[k] << BIN_SHIFT) | (dreg[k] & (BIN_NODES - 1));
            }
        }
    }
}

// ---------------- K2: per-bin fine sort -> CSR + rowptr ----------------
__global__ __launch_bounds__(1024) void fine_kernel(
    const int* __restrict__ bin_cursor, const int* __restrict__ binned,
    int* __restrict__ csr, int* __restrict__ rowptr, int N, int nbins)
{
    __shared__ int a[BIN_NODES];
    __shared__ int cur[BIN_NODES];
    const int b = blockIdx.x;
    const int tid = threadIdx.x;

    const int cnt = min(bin_cursor[b], CAPB);
    int binbase = 0;
    for (int j = 0; j < b; ++j) binbase += min(bin_cursor[j], CAPB);

    const int nn = min(BIN_NODES, N - b * BIN_NODES);
    const int* __restrict__ brec = binned + (long)b * CAPB;

    a[tid] = 0;
    __syncthreads();

    for (int k = tid; k < cnt; k += 1024) {
        atomicAdd(&a[brec[k] & (BIN_NODES - 1)], 1);
    }
    __syncthreads();

    int v = a[tid];
#pragma unroll
    for (int ofs = 1; ofs < BIN_NODES; ofs <<= 1) {
        int t = (tid >= ofs) ? a[tid - ofs] : 0;
        __syncthreads();
        a[tid] += t;
        __syncthreads();
    }
    const int excl = a[tid] - v;

    if (tid < nn) rowptr[b * BIN_NODES + tid] = binbase + excl;
    cur[tid] = binbase + excl;
    if (b == nbins - 1 && tid == 0) rowptr[N] = binbase + cnt;
    __syncthreads();

    for (int k = tid; k < cnt; k += 1024) {
        int rec = brec[k];
        int pos = atomicAdd(&cur[rec & (BIN_NODES - 1)], 1);
        csr[pos] = rec >> BIN_SHIFT;
    }
}

// -------- fused: agg<64> (4 rounds/group) + gemm2 fp16 MFMA ------------------
__global__ __launch_bounds__(256) void agg1_gemm2_kernel(
    const _Float16* __restrict__ h1, const float* __restrict__ as_,
    const float* __restrict__ ad_, const int* __restrict__ rowptr,
    const int* __restrict__ csr, const float* __restrict__ b1,
    const _Float16* __restrict__ w2t,
    _Float16* __restrict__ h2, float* __restrict__ as2, float* __restrict__ ad2,
    int N)
{
    __shared__ __align__(16) _Float16 Xs[64 * XS2];   // 9216 B
    __shared__ int   Ss[16 * AGG_STRIDE];
    __shared__ float Ps[16 * AGG_STRIDE];
    const int tid = threadIdx.x;
    const int dl  = tid >> 4;
    const int sub = tid & 15;
    const int lane = tid & 63;
    const int w = tid >> 6;
    const int rh = w >> 1, ch = w & 1;
    const int m = lane & 31, khalf = lane >> 5;

    // B prefetch from global (w2t 8KB, L1-hot)
    h8_t bfrag[4];
    {
        const _Float16* bp = w2t + (ch * 32 + m) * 64 + khalf * 8;
#pragma unroll
        for (int kc = 0; kc < 4; ++kc)
            bfrag[kc] = *(const h8_t*)(bp + kc * 16);
    }

    int*   __restrict__ sp = &Ss[dl * AGG_STRIDE];
    float* __restrict__ pp = &Ps[dl * AGG_STRIDE];
    const float4 bv = *(const float4*)&b1[sub * 4];

    for (int round = 0; round < 4; ++round) {
        const int row = round * 16 + dl;
        const int i = blockIdx.x * 64 + row;
        const bool alive = (i < N);

        int r0 = 0, deg = 0;
        if (alive) {
            r0 = rowptr[i];
            deg = rowptr[i + 1] - r0;
            if (deg > MAXDEG) deg = MAXDEG;
        }
        const float adi    = alive ? ad_[i] : 0.f;
        const float e_self = alive ? lrelu(as_[i] + adi) : 0.f;

        float psum = 0.f;
        for (int c = sub; c < deg; c += 16) {
            int s = csr[r0 + c];
            float p = __expf(lrelu(as_[s] + adi));
            sp[c] = s;
            pp[c] = p;
            psum += p;
        }
#pragma unroll
        for (int off = 1; off < 16; off <<= 1) psum += __shfl_xor(psum, off);
        const float p_self = __expf(e_self);
        const float inv = 1.f / (psum + p_self);

        const int col = sub * 4;
        float4 acc = make_float4(0.f, 0.f, 0.f, 0.f);
        int k = 0;
        for (; k + 4 <= deg; k += 4) {
            int   sA = sp[k],     sB = sp[k + 1], sC = sp[k + 2], sD = sp[k + 3];
            float pA = pp[k],     pB = pp[k + 1], pC = pp[k + 2], pD = pp[k + 3];
            h4_t hA = *(const h4_t*)&h1[(long)sA * 64 + col];
            h4_t hB = *(const h4_t*)&h1[(long)sB * 64 + col];
            h4_t hC = *(const h4_t*)&h1[(long)sC * 64 + col];
            h4_t hD = *(const h4_t*)&h1[(long)sD * 64 + col];
            acc.x += (float)hA.x * pA + (float)hB.x * pB + (float)hC.x * pC + (float)hD.x * pD;
            acc.y += (float)hA.y * pA + (float)hB.y * pB + (float)hC.y * pC + (float)hD.y * pD;
            acc.z += (float)hA.z * pA + (float)hB.z * pB + (float)hC.z * pC + (float)hD.z * pD;
            acc.w += (float)hA.w * pA + (float)hB.w * pB + (float)hC.w * pC + (float)hD.w * pD;
        }
        for (; k < deg; ++k) {
            int   s = sp[k];
            float p = pp[k];
            h4_t hv = *(const h4_t*)&h1[(long)s * 64 + col];
            acc.x += (float)hv.x * p; acc.y += (float)hv.y * p;
            acc.z += (float)hv.z * p; acc.w += (float)hv.w * p;
        }

        float ox = 0.f, oy = 0.f, oz = 0.f, ow = 0.f;
        if (alive) {
            h4_t hv = *(const h4_t*)&h1[(long)i * 64 + col];   // self loop
            ox = (acc.x + (float)hv.x * p_self) * inv + bv.x;
            oy = (acc.y + (float)hv.y * p_self) * inv + bv.y;
            oz = (acc.z + (float)hv.z * p_self) * inv + bv.z;
            ow = (acc.w + (float)hv.w * p_self) * inv + bv.w;
        }
        h4_t o;                                                // relu + cast
        o.x = (_Float16)fmaxf(ox, 0.f); o.y = (_Float16)fmaxf(oy, 0.f);
        o.z = (_Float16)fmaxf(oz, 0.f); o.w = (_Float16)fmaxf(ow, 0.f);
        *(h4_t*)&Xs[row * XS2 + col] = o;
    }
    __syncthreads();

    // gemm2: h2' = Xs @ W2 (+ as2/ad2 from cols 40/41)
    const _Float16* ax = &Xs[(rh * 32 + m) * XS2 + khalf * 8];
    f16x_t acc2 = {};
#pragma unroll
    for (int kc = 0; kc < 4; ++kc) {
        h8_t a = *(const h8_t*)(ax + kc * 16);
        acc2 = __builtin_amdgcn_mfma_f32_32x32x16_f16(a, bfrag[kc], acc2, 0, 0, 0);
    }

    const int col = ch * 32 + m;
#pragma unroll
    for (int r = 0; r < 16; ++r) {
        int rowl = (r & 3) + 8 * (r >> 2) + 4 * khalf;
        long grow = (long)blockIdx.x * 64 + rh * 32 + rowl;
        float v = acc2[r];
        if (grow < N) {
            if (col < 40)       h2[grow * 40 + col] = (_Float16)v;
            else if (col == 40) as2[grow] = v;
            else if (col == 41) ad2[grow] = v;
        }
    }
}

// -------- aggregation layer 2: one 16-lane group per dst; fp16 gather --------
__global__ __launch_bounds__(256) void aggregate2_kernel(
    const _Float16* __restrict__ h, const float* __restrict__ as_,
    const float* __restrict__ ad_, const int* __restrict__ rowptr,
    const int* __restrict__ csr, const float* __restrict__ bias,
    float* __restrict__ out, int N)
{
    __shared__ int   Ss[16 * AGG_STRIDE];
    __shared__ float Ps[16 * AGG_STRIDE];
    const int tid = threadIdx.x;
    const int dl  = tid >> 4;
    const int sub = tid & 15;
    const int i = blockIdx.x * 16 + dl;
    const bool alive = (i < N);

    int r0 = 0, deg = 0;
    if (alive) {
        r0 = rowptr[i];
        deg = rowptr[i + 1] - r0;
        if (deg > MAXDEG) deg = MAXDEG;
    }
    const float adi    = alive ? ad_[i] : 0.f;
    const float e_self = alive ? lrelu(as_[i] + adi) : 0.f;

    int*   __restrict__ sp = &Ss[dl * AGG_STRIDE];
    float* __restrict__ pp = &Ps[dl * AGG_STRIDE];

    float psum = 0.f;
    for (int c = sub; c < deg; c += 16) {
        int s = csr[r0 + c];
        float p = __expf(lrelu(as_[s] + adi));
        sp[c] = s;
        pp[c] = p;
        psum += p;
    }
#pragma unroll
    for (int off = 1; off < 16; off <<= 1) psum += __shfl_xor(psum, off);
    const float p_self = __expf(e_self);
    const float inv = 1.f / (psum + p_self);

    const bool act = (sub * 4 < 40);
    const int  col = act ? sub * 4 : 0;
    float4 acc = make_float4(0.f, 0.f, 0.f, 0.f);

    int k = 0;
    for (; k + 4 <= deg; k += 4) {
        int   sA = sp[k],     sB = sp[k + 1], sC = sp[k + 2], sD = sp[k + 3];
        float pA = pp[k],     pB = pp[k + 1], pC = pp[k + 2], pD = pp[k + 3];
        if (act) {
            h4_t hA = *(const h4_t*)&h[(long)sA * 40 + col];
            h4_t hB = *(const h4_t*)&h[(long)sB * 40 + col];
            h4_t hC = *(const h4_t*)&h[(long)sC * 40 + col];
            h4_t hD = *(const h4_t*)&h[(long)sD * 40 + col];
            acc.x += (float)hA.x * pA + (float)hB.x * pB + (float)hC.x * pC + (float)hD.x * pD;
            acc.y += (float)hA.y * pA + (float)hB.y * pB + (float)hC.y * pC + (float)hD.y * pD;
            acc.z += (float)hA.z * pA + (float)hB.z * pB + (float)hC.z * pC + (float)hD.z * pD;
            acc.w += (float)hA.w * pA + (float)hB.w * pB + (float)hC.w * pC + (float)hD.w * pD;
        }
    }
    for (; k < deg; ++k) {
        int   s = sp[k];
        float p = pp[k];
        if (act) {
            h4_t hv = *(const h4_t*)&h[(long)s * 40 + col];
            acc.x += (float)hv.x * p; acc.y += (float)hv.y * p;
            acc.z += (float)hv.z * p; acc.w += (float)hv.w * p;
        }
    }

    if (alive && act) {
        h4_t hv = *(const h4_t*)&h[(long)i * 40 + col];   // self loop
        float4 bv = *(const float4*)&bias[col];
        float4 o;
        o.x = (acc.x + (float)hv.x * p_self) * inv + bv.x;
        o.y = (acc.y + (float)hv.y * p_self) * inv + bv.y;
        o.z = (acc.z + (float)hv.z * p_self) * inv + bv.z;
        o.w = (acc.w + (float)hv.w * p_self) * inv + bv.w;
        *(float4*)&out[(long)i * 40 + col] = o;
    }
}

extern "C" void kernel_launch(void* const* d_in, const int* in_sizes, int n_in,
                              void* d_out, int out_size, void* d_ws, size_t ws_size,
                              hipStream_t stream) {
    const float* x    = (const float*)d_in[0];
    const int*   ei   = (const int*)d_in[1];
    const float* W1   = (const float*)d_in[2];
    const float* at_s1= (const float*)d_in[3];
    const float* at_d1= (const float*)d_in[4];
    const float* b1   = (const float*)d_in[5];
    const float* W2   = (const float*)d_in[6];
    const float* at_s2= (const float*)d_in[7];
    const float* at_d2= (const float*)d_in[8];
    const float* b2   = (const float*)d_in[9];
    float* out = (float*)d_out;

    const int N = in_sizes[0] / 128;   // 100000
    const int E = in_sizes[1] / 2;     // 1600000
    const int nbins = (N + BIN_NODES - 1) >> BIN_SHIFT;  // 98

    char* p = (char*)d_ws;
    auto carve = [&](size_t bytes) -> void* {
        void* r = (void*)p;
        p += (bytes + 255) & ~(size_t)255;
        return r;
    };
    int*       bin_cursor = (int*)      carve((size_t)MAXBINS * 4);
    int*       binned     = (int*)      carve((size_t)nbins * CAPB * 4);
    int*       csr        = (int*)      carve((size_t)E * 4);
    int*       rowptr     = (int*)      carve((size_t)(N + 1) * 4);
    _Float16*  w1t        = (_Float16*) carve((size_t)8192 * 2);
    _Float16*  w2t        = (_Float16*) carve((size_t)4096 * 2);
    float*     u1         = (float*)    carve((size_t)128 * 4);
    float*     v1         = (float*)    carve((size_t)128 * 4);
    _Float16*  h1         = (_Float16*) carve((size_t)N * 64 * 2);
    _Float16*  h2         = (_Float16*) carve((size_t)N * 40 * 2);
    float*     asn        = (float*)    carve((size_t)N * 4);
    float*     adn        = (float*)    carve((size_t)N * 4);
    float*     asn2       = (float*)    carve((size_t)N * 4);
    float*     adn2       = (float*)    carve((size_t)N * 4);

    hipMemsetAsync(bin_cursor, 0, (size_t)MAXBINS * 4, stream);

    prep_kernel<<<2, 256, 0, stream>>>(W1, W2, at_s1, at_d1, at_s2, at_d2,
                                       w1t, w2t, u1, v1);

    const int bb = (E + K1_CHUNK - 1) / K1_CHUNK;        // bin blocks (first)
    const int gb = (N + 63) / 64;                        // gemm1 blocks
    gemm1_bin_kernel<<<bb + gb, 256, 0, stream>>>(
        x, w1t, u1, v1, h1, asn, adn, N, bb,
        ei, ei + E, E, nbins, bin_cursor, binned);

    fine_kernel<<<nbins, 1024, 0, stream>>>(bin_cursor, binned, csr, rowptr, N, nbins);

    agg1_gemm2_kernel<<<(N + 63) / 64, 256, 0, stream>>>(
        h1, asn, adn, rowptr, csr, b1, w2t, h2, asn2, adn2, N);

    aggregate2_kernel<<<(N + 15) / 16, 256, 0, stream>>>(
        h2, asn2, adn2, rowptr, csr, b2, out, N);
}